// Round 19
// baseline (603.955 us; speedup 1.0000x reference)
//
#include <hip/hip_runtime.h>
#include <hip/hip_bf16.h>
#include <stdint.h>

// Problem constants
#define TOK 8192   // B*S
#define HD  1024   // H
#define FD  4096   // F
#define NE  8      // experts
#define BK  32     // K-step

// Workspace layout (bytes). Total ~278 MB.
#define WS_CNT 0
#define WS_RW  1024
#define WS_LST 131072
#define WS_PRB 524288
#define WS_PART 786432
#define WS_XB  ((size_t)1  << 20)   // xb: 8192*1024*2   = 16 MiB
#define WS_W1T ((size_t)18 << 20)   // W1T: 8*4096*1024*2 = 64 MiB
#define WS_W2T ((size_t)84 << 20)   // W2T: 8*1024*4096*2 = 64 MiB
#define WS_H   ((size_t)150 << 20)  // hbuf: 16384*4096*2 = 128 MiB
#define WS_Y   WS_W1T               // ybuf overlays W1T (dead after gemm1)

typedef __attribute__((ext_vector_type(4))) float  f32x4;
typedef __attribute__((ext_vector_type(8))) short  s16x8;
typedef __attribute__((ext_vector_type(4))) short  s16x4;
typedef __attribute__((ext_vector_type(8))) __bf16 bf16x8;

__device__ inline unsigned short f2bf(float f) {
    __hip_bfloat16 h = __float2bfloat16(f);   // RNE
    return __builtin_bit_cast(unsigned short, h);
}
__device__ inline float bf2f(unsigned short s) {
    unsigned u = ((unsigned)s) << 16;
    return __builtin_bit_cast(float, u);
}
__device__ inline f32x4 mfma_bf16(s16x8 a, s16x8 b, f32x4 c) {
    return __builtin_amdgcn_mfma_f32_16x16x32_bf16(
        __builtin_bit_cast(bf16x8, a), __builtin_bit_cast(bf16x8, b), c, 0, 0, 0);
}
// async global->LDS, 16B per lane. LDS dest wave-uniform base (+lane*16 implicit).
__device__ inline void gl2lds16(const void* g, void* l) {
    __builtin_amdgcn_global_load_lds(
        (const __attribute__((address_space(1))) unsigned int*)g,
        (__attribute__((address_space(3))) unsigned int*)l, 16, 0, 0);
}

// Cheap exact-identity tanh-GELU: 0.5u(1+tanh z) == u*p/(1+t), t=e^{-2|z|}, p=(z>=0?1:t).
__device__ inline float gelu_fast(float u) {
    float u2 = u * u;
    float z  = u * fmaf(u2, 0.0356774081f, 0.7978845608f);
    float t  = exp2f(fabsf(z) * -2.885390082f);   // e^{-2|z|}
    float p  = (z >= 0.f) ? 1.f : t;
    return __fdividef(u * p, 1.f + t);
}

// 64x64 transpose tile (r18-verified math): src [R][C] fp32 -> dst [C][R] bf16
__device__ inline void transpose_tile64(
    const float* s, unsigned short* d, int R, int C,
    unsigned short (*tile)[65], int tid)
{
    int cg = tid & 15;                     // col group of 4
    int rg = tid >> 4;                     // 0..15
    #pragma unroll
    for (int i = 0; i < 4; ++i) {
        int r = i * 16 + rg;
        f32x4 v = *(const f32x4*)&s[(size_t)r * C + cg * 4];
        tile[r][cg * 4 + 0] = f2bf(v[0]); tile[r][cg * 4 + 1] = f2bf(v[1]);
        tile[r][cg * 4 + 2] = f2bf(v[2]); tile[r][cg * 4 + 3] = f2bf(v[3]);
    }
    __syncthreads();
    int hq = (tid & 15) * 4;
    int fb = tid >> 4;
    #pragma unroll
    for (int i = 0; i < 4; ++i) {
        int c = i * 16 + fb;
        s16x4 v;
        v[0] = (short)tile[hq + 0][c]; v[1] = (short)tile[hq + 1][c];
        v[2] = (short)tile[hq + 2][c]; v[3] = (short)tile[hq + 3][c];
        *(s16x4*)&d[(size_t)c * R + hq] = v;
    }
}

// ======== Prep (r19): W1 transpose + router only. W2 transpose moved into gemm1's ========
// dispatch (w2t not needed until gemm2; stream order guarantees completion — r15's
// proven overlap mechanism extended). grid = (1280, NE): x<1024 -> W1 tile (y=expert);
// x>=1024 -> router block rb=(x-1024)*NE + y.
__global__ __launch_bounds__(256) void prep_kernel(
    const float* __restrict__ W1, unsigned short* __restrict__ w1t,
    const float* __restrict__ x, const float* __restrict__ Wr,
    const float* __restrict__ br, int* __restrict__ cnt,
    int* __restrict__ lists, float* __restrict__ rw,
    float* __restrict__ probs, unsigned short* __restrict__ xb)
{
    __shared__ unsigned short tile[64][65];
    if (blockIdx.x < 1024) {
        // W1: R=HD, C=FD; 64 c-tiles x 16 r-tiles
        int id = blockIdx.x;
        int p  = blockIdx.y;
        int c0 = (id & 63) * 64, r0 = (id >> 6) * 64;
        const float* s = W1 + ((size_t)p * HD + r0) * FD + c0;
        unsigned short* d = w1t + ((size_t)p * FD + c0) * HD + r0;
        transpose_tile64(s, d, HD, FD, tile, threadIdx.x);
    } else {
        // ---------------- router path (identical math to r18) ----------------
        int rb   = (blockIdx.x - 1024) * NE + blockIdx.y;   // 0..2047
        int gid  = rb * 256 + threadIdx.x;
        int tok  = gid >> 6;
        int lane = threadIdx.x & 63;
        const float* xr = x + (size_t)tok * HD;
        unsigned short* xbr = xb + (size_t)tok * HD;
        float acc[NE] = {0.f,0.f,0.f,0.f,0.f,0.f,0.f,0.f};
        #pragma unroll
        for (int i = 0; i < 4; ++i) {
            int h0 = i * 256 + lane * 4;
            f32x4 xv = *(const f32x4*)&xr[h0];
            s16x4 xo;
            xo[0] = (short)f2bf(xv[0]); xo[1] = (short)f2bf(xv[1]);
            xo[2] = (short)f2bf(xv[2]); xo[3] = (short)f2bf(xv[3]);
            *(s16x4*)&xbr[h0] = xo;
            #pragma unroll
            for (int j = 0; j < 4; ++j) {
                const f32x4* w = (const f32x4*)(Wr + (size_t)(h0 + j) * NE);
                f32x4 w0 = w[0], w1 = w[1];
                float xs = xv[j];
                acc[0] += xs * w0[0]; acc[1] += xs * w0[1];
                acc[2] += xs * w0[2]; acc[3] += xs * w0[3];
                acc[4] += xs * w1[0]; acc[5] += xs * w1[1];
                acc[6] += xs * w1[2]; acc[7] += xs * w1[3];
            }
        }
        #pragma unroll
        for (int e = 0; e < NE; ++e) {
            float v = acc[e];
            #pragma unroll
            for (int off = 32; off > 0; off >>= 1) v += __shfl_down(v, off);
            acc[e] = v;
        }
        if (lane == 0) {
            float lg[NE];
            #pragma unroll
            for (int e = 0; e < NE; ++e) lg[e] = acc[e] + br[e];
            float m = lg[0];
            #pragma unroll
            for (int e = 1; e < NE; ++e) m = fmaxf(m, lg[e]);
            float s = 0.f, p[NE];
            #pragma unroll
            for (int e = 0; e < NE; ++e) { p[e] = __expf(lg[e] - m); s += p[e]; }
            float inv = 1.f / s;
            f32x4 p0 = {p[0]*inv, p[1]*inv, p[2]*inv, p[3]*inv};
            f32x4 p1 = {p[4]*inv, p[5]*inv, p[6]*inv, p[7]*inv};
            *(f32x4*)&probs[(size_t)tok * NE]     = p0;
            *(f32x4*)&probs[(size_t)tok * NE + 4] = p1;
            int e0 = 0;
            #pragma unroll
            for (int e = 1; e < NE; ++e) if (lg[e] > lg[e0]) e0 = e;
            int e1 = (e0 == 0) ? 1 : 0;
            #pragma unroll
            for (int e = 0; e < NE; ++e) if (e != e0 && lg[e] > lg[e1]) e1 = e;
            float t1 = __expf(lg[e1] - lg[e0]);
            float w0 = 1.f / (1.f + t1);
            rw[tok * 2 + 0] = w0;
            rw[tok * 2 + 1] = t1 * w0;
            int p0i = atomicAdd(&cnt[e0], 1);
            lists[e0 * TOK + p0i] = (tok << 1);
            int p1i = atomicAdd(&cnt[e1], 1);
            lists[e1 * TOK + p1i] = (tok << 1) | 1;
        }
    }
}

// ======= GEMM machinery: 192M x 256N block, 4 waves (2Mx2N), wave 96x128, ring-2 =======
// LDS-PIPE MODEL (confirmed r12/r13): FLOP/LDS-byte = Mw*Nw/(Mw+Nw) = 49.2.
// LDS = ring-2 x (A[192x32] 12KB + B[256x32] 16KB) = 56 KB -> 2 blocks/CU.
// Ring-2 schedule (7 loads/thread/stage -> vmcnt(7)); compact 192-row-panel grid.

#define GEMM_FIND_EXPERT()                                                     \
    int pb = blockIdx.y;                                                       \
    int e = 0, row0 = -1, nc = 0, base = 0;                                    \
    {                                                                          \
        int accb = 0, pref = 0;                                                \
        _Pragma("unroll")                                                      \
        for (int i = 0; i < NE; ++i) {                                         \
            int c = cnt[i];                                                    \
            int nb = (c + 191) / 192;                                          \
            if (row0 < 0 && pb < accb + nb) {                                  \
                e = i; row0 = (pb - accb) * 192; nc = c; base = pref;          \
            }                                                                  \
            accb += nb; pref += c;                                             \
        }                                                                      \
        if (row0 < 0) return;                                                  \
    }

#define GEMM_STAGE(kt3, b3)                                                    \
    {                                                                          \
        gl2lds16(ga[0] + (size_t)(kt3) * BK, &As[b3][(0 * 256 + w * 64) * 8]); \
        gl2lds16(ga[1] + (size_t)(kt3) * BK, &As[b3][(1 * 256 + w * 64) * 8]); \
        gl2lds16(ga[2] + (size_t)(kt3) * BK, &As[b3][(2 * 256 + w * 64) * 8]); \
        gl2lds16(gb[0] + (size_t)(kt3) * BK, &Bs[b3][(0 * 256 + w * 64) * 8]); \
        gl2lds16(gb[1] + (size_t)(kt3) * BK, &Bs[b3][(1 * 256 + w * 64) * 8]); \
        gl2lds16(gb[2] + (size_t)(kt3) * BK, &Bs[b3][(2 * 256 + w * 64) * 8]); \
        gl2lds16(gb[3] + (size_t)(kt3) * BK, &Bs[b3][(3 * 256 + w * 64) * 8]); \
    }

#define GEMM_COMPUTE(b)                                                        \
    {                                                                          \
        s16x8 af[6];                                                           \
        _Pragma("unroll")                                                      \
        for (int a = 0; a < 6; ++a) {                                          \
            int r = wr * 96 + a * 16 + rl;                                     \
            af[a] = *(const s16x8*)&As[b][r * 32 + ((q ^ ((r >> 1) & 3)) << 3)]; \
        }                                                                      \
        _Pragma("unroll")                                                      \
        for (int nh = 0; nh < 2; ++nh) {                                       \
            s16x8 bfr[4];                                                      \
            _Pragma("unroll")                                                  \
            for (int ni = 0; ni < 4; ++ni) {                                   \
                int n = wc * 128 + nh * 64 + ni * 16 + rl;                     \
                bfr[ni] = *(const s16x8*)&Bs[b][n * 32 + ((q ^ ((n >> 1) & 3)) << 3)]; \
            }                                                                  \
            _Pragma("unroll")                                                  \
            for (int a = 0; a < 6; ++a)                                        \
                _Pragma("unroll")                                              \
                for (int ni = 0; ni < 4; ++ni)                                 \
                    acc[a][nh * 4 + ni] = mfma_bf16(af[a], bfr[ni], acc[a][nh * 4 + ni]); \
        }                                                                      \
    }

#define GEMM_MAINLOOP(NT)                                                      \
    GEMM_STAGE(0, 0);                                                          \
    for (int kt = 0; kt < (NT); ++kt) {                                        \
        __builtin_amdgcn_s_barrier();                                          \
        if (kt + 1 < (NT)) {                                                   \
            GEMM_STAGE(kt + 1, (kt + 1) & 1);                                  \
            asm volatile("s_waitcnt vmcnt(7)" ::: "memory");                   \
        } else {                                                               \
            asm volatile("s_waitcnt vmcnt(0)" ::: "memory");                   \
        }                                                                      \
        __builtin_amdgcn_s_barrier();                                          \
        GEMM_COMPUTE(kt & 1);                                                  \
    }

// ---------------- GEMM1: hbuf[base+row] = gelu(xb[tok(row)] @ W1T[e]^T + b1[e]) ----------------
// grid (16, 94 + 512): y<94 -> GEMM row-panels (dispatched FIRST); y>=94 -> one 64x64
// W2-transpose tile each (8192 tiles), overlapped with the GEMM blocks (w2t needed
// only by gemm2; stream order guarantees completion). LDS for transpose aliased into As.
__global__ __launch_bounds__(256, 2) void gemm1_kernel(
    const unsigned short* __restrict__ xb, const unsigned short* __restrict__ w1t,
    const float* __restrict__ b1, const int* __restrict__ cnt,
    const int* __restrict__ lists, unsigned short* __restrict__ hbuf,
    const float* __restrict__ W2, unsigned short* __restrict__ w2t)
{
    __shared__ unsigned short As[2][192 * BK];   // 2 x 12 KiB
    __shared__ unsigned short Bs[2][256 * BK];   // 2 x 16 KiB

    if (blockIdx.y >= 94) {
        // W2-transpose block: tile t of 8192. W2: R=FD, C=HD; 16 c-tiles x 64 r-tiles.
        int t  = (blockIdx.y - 94) * 16 + blockIdx.x;   // 0..8191
        int p  = t >> 10;                               // expert
        int tt = t & 1023;
        int c0 = (tt & 15) * 64, r0 = (tt >> 4) * 64;
        const float* s = W2 + ((size_t)p * FD + r0) * HD + c0;
        unsigned short* d = w2t + ((size_t)p * HD + c0) * FD + r0;
        transpose_tile64(s, d, FD, HD, (unsigned short(*)[65])&As[0][0], threadIdx.x);
        return;
    }

    GEMM_FIND_EXPERT()
    int cb = blockIdx.x * 256;

    int tid  = threadIdx.x;
    int lane = tid & 63;
    int w    = tid >> 6;     // 0..3
    int wr   = w >> 1;       // M half (rows wr*96..+96)
    int wc   = w & 1;        // N half (cols wc*128..+128)
    int rl   = lane & 15;
    int q    = lane >> 4;    // k-chunk 0..3

    const unsigned short* ga[3];
    const unsigned short* gb[4];
    #pragma unroll
    for (int i = 0; i < 3; ++i) {
        int ch  = i * 256 + tid;
        int row = ch >> 2;
        int kc  = (ch & 3) ^ ((row >> 1) & 3);
        int lr  = row0 + row;
        int tok = (lr < nc) ? (lists[e * TOK + lr] >> 1) : 0;
        ga[i] = xb + (size_t)tok * HD + kc * 8;
    }
    #pragma unroll
    for (int i = 0; i < 4; ++i) {
        int ch  = i * 256 + tid;
        int row = ch >> 2;
        int kc  = (ch & 3) ^ ((row >> 1) & 3);
        gb[i] = w1t + ((size_t)e * FD + cb + row) * HD + kc * 8;
    }

    f32x4 acc[6][8];
    #pragma unroll
    for (int i = 0; i < 6; ++i)
        #pragma unroll
        for (int j = 0; j < 8; ++j) acc[i][j] = (f32x4){0.f, 0.f, 0.f, 0.f};

    GEMM_MAINLOOP(HD / BK)   // 32 iters

    // epilogue: + b1, gelu_fast, bf16 store, expert-packed rows
    int col0 = cb + wc * 128 + rl;
    float b1v[8];
    #pragma unroll
    for (int k = 0; k < 8; ++k)
        b1v[k] = b1[e * FD + col0 + (k >> 2) * 64 + (k & 3) * 16];
    #pragma unroll
    for (int a = 0; a < 6; ++a) {
        #pragma unroll
        for (int j = 0; j < 4; ++j) {
            int grow = row0 + wr * 96 + a * 16 + q * 4 + j;
            if (grow < nc) {
                unsigned short* dst = hbuf + (size_t)(base + grow) * FD + col0;
                #pragma unroll
                for (int k = 0; k < 8; ++k)
                    dst[(k >> 2) * 64 + (k & 3) * 16] =
                        f2bf(gelu_fast(acc[a][k][j] + b1v[k]));
            }
        }
    }
}

// ---------------- GEMM2: y = hbuf[base+row] @ W2T[e]^T + b2[e], scatter to ybuf ----------------
__global__ __launch_bounds__(256, 2) void gemm2_kernel(
    const unsigned short* __restrict__ hbuf, const unsigned short* __restrict__ w2t,
    const float* __restrict__ b2, const int* __restrict__ cnt,
    const int* __restrict__ lists, unsigned short* __restrict__ ybuf)
{
    GEMM_FIND_EXPERT()
    int cb = blockIdx.x * 256;

    __shared__ unsigned short As[2][192 * BK];
    __shared__ unsigned short Bs[2][256 * BK];

    int tid  = threadIdx.x;
    int lane = tid & 63;
    int w    = tid >> 6;
    int wr   = w >> 1;
    int wc   = w & 1;
    int rl   = lane & 15;
    int q    = lane >> 4;

    const unsigned short* ga[3];
    const unsigned short* gb[4];
    #pragma unroll
    for (int i = 0; i < 3; ++i) {
        int ch  = i * 256 + tid;
        int row = ch >> 2;
        int kc  = (ch & 3) ^ ((row >> 1) & 3);
        int lr  = row0 + row;
        int hrow = base + ((lr < nc) ? lr : (nc - 1));
        ga[i] = hbuf + (size_t)hrow * FD + kc * 8;
    }
    #pragma unroll
    for (int i = 0; i < 4; ++i) {
        int ch  = i * 256 + tid;
        int row = ch >> 2;
        int kc  = (ch & 3) ^ ((row >> 1) & 3);
        gb[i] = w2t + ((size_t)e * HD + cb + row) * FD + kc * 8;
    }

    f32x4 acc[6][8];
    #pragma unroll
    for (int i = 0; i < 6; ++i)
        #pragma unroll
        for (int j = 0; j < 8; ++j) acc[i][j] = (f32x4){0.f, 0.f, 0.f, 0.f};

    GEMM_MAINLOOP(FD / BK)   // 128 iters

    int col0 = cb + wc * 128 + rl;
    float b2v[8];
    #pragma unroll
    for (int k = 0; k < 8; ++k)
        b2v[k] = b2[e * HD + col0 + (k >> 2) * 64 + (k & 3) * 16];
    #pragma unroll
    for (int a = 0; a < 6; ++a) {
        #pragma unroll
        for (int j = 0; j < 4; ++j) {
            int grow = row0 + wr * 96 + a * 16 + q * 4 + j;
            if (grow < nc) {
                int entry = lists[e * TOK + grow];
                unsigned short* dst = ybuf + ((size_t)((entry & 1) * TOK + (entry >> 1))) * HD + col0;
                #pragma unroll
                for (int k = 0; k < 8; ++k)
                    dst[(k >> 2) * 64 + (k & 3) * 16] = f2bf(acc[a][k][j] + b2v[k]);
            }
        }
    }
}

// -------- Fused epilogue: gather (out = w0*y0 + w1*y1) + aux1 partial sums --------
__global__ __launch_bounds__(256) void gather_aux_kernel(
    const unsigned short* __restrict__ ybuf, const float* __restrict__ rw,
    float* __restrict__ out, const float* __restrict__ probs,
    float* __restrict__ partial)
{
    if (blockIdx.x < 4096) {
        int g = blockIdx.x * 256 + threadIdx.x;
        int t = g >> 7;
        int h0 = (g & 127) * 8;
        float w0 = rw[t * 2 + 0];
        float w1 = rw[t * 2 + 1];
        s16x8 y0 = *(const s16x8*)&ybuf[(size_t)t * HD + h0];
        s16x8 y1 = *(const s16x8*)&ybuf[((size_t)TOK + t) * HD + h0];
        f32x4 o0, o1;
        #pragma unroll
        for (int j = 0; j < 4; ++j) {
            o0[j] = w0 * bf2f((unsigned short)y0[j])   + w1 * bf2f((unsigned short)y1[j]);
            o1[j] = w0 * bf2f((unsigned short)y0[j+4]) + w1 * bf2f((unsigned short)y1[j+4]);
        }
        *(f32x4*)&out[(size_t)t * HD + h0]     = o0;
        *(f32x4*)&out[(size_t)t * HD + h0 + 4] = o1;
    } else {
        __shared__ float sm[256 * NE];
        int bb  = blockIdx.x - 4096;
        int tid = threadIdx.x;
        int t = bb * 256 + tid;
        const f32x4* p = (const f32x4*)&probs[(size_t)t * NE];
        f32x4 a = p[0], b = p[1];
        sm[tid*NE+0]=a[0]; sm[tid*NE+1]=a[1]; sm[tid*NE+2]=a[2]; sm[tid*NE+3]=a[3];
        sm[tid*NE+4]=b[0]; sm[tid*NE+5]=b[1]; sm[tid*NE+6]=b[2]; sm[tid*NE+7]=b[3];
        __syncthreads();
        for (int s = 128; s > 0; s >>= 1) {
            if (tid < s) {
                #pragma unroll
                for (int e2 = 0; e2 < NE; ++e2)
                    sm[tid * NE + e2] += sm[(tid + s) * NE + e2];
            }
            __syncthreads();
        }
        if (tid < NE) partial[bb * NE + tid] = sm[tid];
    }
}

__global__ __launch_bounds__(64) void aux2_kernel(
    const float* __restrict__ partial, float* __restrict__ outAux)
{
    __shared__ float sm[NE];
    int tid = threadIdx.x;
    if (tid < NE) {
        float s = 0.f;
        for (int b = 0; b < 32; ++b) s += partial[b * NE + tid];
        sm[tid] = s;
    }
    __syncthreads();
    if (tid == 0) {
        float ssum = 0.f;
        #pragma unroll
        for (int e2 = 0; e2 < NE; ++e2) {
            float v = sm[e2] * (1.f / (float)TOK);
            ssum += v * v;
        }
        outAux[0] = (float)NE * ssum;
    }
}

extern "C" void kernel_launch(void* const* d_in, const int* in_sizes, int n_in,
                              void* d_out, int out_size, void* d_ws, size_t ws_size,
                              hipStream_t stream) {
    const float* x  = (const float*)d_in[0];
    const float* W1 = (const float*)d_in[1];
    const float* b1 = (const float*)d_in[2];
    const float* W2 = (const float*)d_in[3];
    const float* b2 = (const float*)d_in[4];
    const float* Wr = (const float*)d_in[5];
    const float* br = (const float*)d_in[6];
    float* out = (float*)d_out;
    char* ws = (char*)d_ws;

    int*   cnt   = (int*)(ws + WS_CNT);
    float* rw    = (float*)(ws + WS_RW);
    int*   lists = (int*)(ws + WS_LST);
    float* probs = (float*)(ws + WS_PRB);
    float* part  = (float*)(ws + WS_PART);
    unsigned short* xb   = (unsigned short*)(ws + WS_XB);
    unsigned short* w1t  = (unsigned short*)(ws + WS_W1T);
    unsigned short* w2t  = (unsigned short*)(ws + WS_W2T);
    unsigned short* hbuf = (unsigned short*)(ws + WS_H);
    unsigned short* ybuf = (unsigned short*)(ws + WS_Y);

    hipMemsetAsync(ws, 0, 64, stream);  // zero cnt
    // Prep: W1 transpose (x<1024) + router (x>=1024); W2 transpose rides in gemm1.
    prep_kernel<<<dim3(1280, NE), 256, 0, stream>>>(W1, w1t,
                                                    x, Wr, br, cnt, lists, rw, probs, xb);
    // gemm1: GEMM panels (y<94, dispatched first) + 8192 W2-transpose tiles (y>=94)
    gemm1_kernel<<<dim3(FD / 256, 94 + 512), 256, 0, stream>>>(
        xb, w1t, b1, cnt, lists, hbuf, W2, w2t);
    gemm2_kernel<<<dim3(HD / 256, 94), 256, 0, stream>>>(hbuf, w2t, b2, cnt, lists, ybuf);
    gather_aux_kernel<<<4096 + 32, 256, 0, stream>>>(ybuf, rw, out, probs, part);
    aux2_kernel<<<1, 64, 0, stream>>>(part, out + (size_t)TOK * HD);
}

// Round 20
// 589.529 us; speedup vs baseline: 1.0245x; 1.0245x over previous
//
#include <hip/hip_runtime.h>
#include <hip/hip_bf16.h>
#include <stdint.h>

// Problem constants
#define TOK 8192   // B*S
#define HD  1024   // H
#define FD  4096   // F
#define NE  8      // experts
#define BK  32     // K-step

// Workspace layout (bytes). Total ~278 MB.
#define WS_CNT 0
#define WS_RW  1024
#define WS_LST 131072
#define WS_PRB 524288
#define WS_PART 786432
#define WS_XB  ((size_t)1  << 20)   // xb: 8192*1024*2   = 16 MiB
#define WS_W1T ((size_t)18 << 20)   // W1T: 8*4096*1024*2 = 64 MiB
#define WS_W2T ((size_t)84 << 20)   // W2T: 8*1024*4096*2 = 64 MiB
#define WS_H   ((size_t)150 << 20)  // hbuf: 16384*4096*2 = 128 MiB
#define WS_Y   WS_W1T               // ybuf overlays W1T (dead after gemm1)

typedef __attribute__((ext_vector_type(4))) float  f32x4;
typedef __attribute__((ext_vector_type(8))) short  s16x8;
typedef __attribute__((ext_vector_type(4))) short  s16x4;
typedef __attribute__((ext_vector_type(8))) __bf16 bf16x8;

__device__ inline unsigned short f2bf(float f) {
    __hip_bfloat16 h = __float2bfloat16(f);   // RNE
    return __builtin_bit_cast(unsigned short, h);
}
__device__ inline float bf2f(unsigned short s) {
    unsigned u = ((unsigned)s) << 16;
    return __builtin_bit_cast(float, u);
}
__device__ inline f32x4 mfma_bf16(s16x8 a, s16x8 b, f32x4 c) {
    return __builtin_amdgcn_mfma_f32_16x16x32_bf16(
        __builtin_bit_cast(bf16x8, a), __builtin_bit_cast(bf16x8, b), c, 0, 0, 0);
}
// async global->LDS, 16B per lane. LDS dest wave-uniform base (+lane*16 implicit).
__device__ inline void gl2lds16(const void* g, void* l) {
    __builtin_amdgcn_global_load_lds(
        (const __attribute__((address_space(1))) unsigned int*)g,
        (__attribute__((address_space(3))) unsigned int*)l, 16, 0, 0);
}

// Cheap exact-identity tanh-GELU: 0.5u(1+tanh z) == u*p/(1+t), t=e^{-2|z|}, p=(z>=0?1:t).
__device__ inline float gelu_fast(float u) {
    float u2 = u * u;
    float z  = u * fmaf(u2, 0.0356774081f, 0.7978845608f);
    float t  = exp2f(fabsf(z) * -2.885390082f);   // e^{-2|z|}
    float p  = (z >= 0.f) ? 1.f : t;
    return __fdividef(u * p, 1.f + t);
}

// ======== Fused prep (r20 = r18, session-best config) ========
// Session evidence: r16 (32KB-LDS tiles, occupancy drop), r17 (same + conflict fix),
// r19 (W2 moved into gemm1) ALL regressed vs this simple form. Prep has a ~200us
// latency-bound component insensitive to transpose volume; the 64x64/8.3KB structure
// at 67% occupancy is the best measured (589-591us total).
// grid = (2304, NE): x<2048 -> transpose tile (x<1024: W1, else W2; y=expert);
// x>=2048 -> router block rb=(x-2048)*NE + y.
__global__ __launch_bounds__(256) void prep_kernel(
    const float* __restrict__ W1, unsigned short* __restrict__ w1t,
    const float* __restrict__ W2, unsigned short* __restrict__ w2t,
    const float* __restrict__ x, const float* __restrict__ Wr,
    const float* __restrict__ br, int* __restrict__ cnt,
    int* __restrict__ lists, float* __restrict__ rw,
    float* __restrict__ probs, unsigned short* __restrict__ xb)
{
    __shared__ unsigned short tile[64][65];
    if (blockIdx.x < 2048) {
        // ---------------- transpose path ----------------
        int id = blockIdx.x;
        int p  = blockIdx.y;
        const float* src; unsigned short* dst; int R, C, r0, c0;
        if (id < 1024) {                       // W1: C/64 = 64 tiles, R/64 = 16
            src = W1; dst = w1t; R = HD; C = FD;
            c0 = (id & 63) * 64; r0 = (id >> 6) * 64;
        } else {                               // W2: C/64 = 16 tiles, R/64 = 64
            int j = id - 1024;
            src = W2; dst = w2t; R = FD; C = HD;
            c0 = (j & 15) * 64; r0 = (j >> 4) * 64;
        }
        const float* s = src + ((size_t)p * R + r0) * C + c0;
        // load phase: f32x4 per thread (16 B), 4 iters; 16 lanes cover one 256-B row
        int cg = threadIdx.x & 15;             // col group of 4
        int rg = threadIdx.x >> 4;             // 0..15
        #pragma unroll
        for (int i = 0; i < 4; ++i) {
            int r = i * 16 + rg;
            f32x4 v = *(const f32x4*)&s[(size_t)r * C + cg * 4];
            tile[r][cg * 4 + 0] = f2bf(v[0]); tile[r][cg * 4 + 1] = f2bf(v[1]);
            tile[r][cg * 4 + 2] = f2bf(v[2]); tile[r][cg * 4 + 3] = f2bf(v[3]);
        }
        __syncthreads();
        // store phase: s16x4 (8 B)
        unsigned short* d = dst + ((size_t)p * C + c0) * R + r0;
        int hq = (threadIdx.x & 15) * 4;
        int fb = threadIdx.x >> 4;
        #pragma unroll
        for (int i = 0; i < 4; ++i) {
            int c = i * 16 + fb;
            s16x4 v;
            v[0] = (short)tile[hq + 0][c]; v[1] = (short)tile[hq + 1][c];
            v[2] = (short)tile[hq + 2][c]; v[3] = (short)tile[hq + 3][c];
            *(s16x4*)&d[(size_t)c * R + hq] = v;
        }
    } else {
        // ---------------- router path ----------------
        int rb   = (blockIdx.x - 2048) * NE + blockIdx.y;   // 0..2047
        int gid  = rb * 256 + threadIdx.x;
        int tok  = gid >> 6;
        int lane = threadIdx.x & 63;
        const float* xr = x + (size_t)tok * HD;
        unsigned short* xbr = xb + (size_t)tok * HD;
        float acc[NE] = {0.f,0.f,0.f,0.f,0.f,0.f,0.f,0.f};
        #pragma unroll
        for (int i = 0; i < 4; ++i) {
            int h0 = i * 256 + lane * 4;
            f32x4 xv = *(const f32x4*)&xr[h0];
            s16x4 xo;
            xo[0] = (short)f2bf(xv[0]); xo[1] = (short)f2bf(xv[1]);
            xo[2] = (short)f2bf(xv[2]); xo[3] = (short)f2bf(xv[3]);
            *(s16x4*)&xbr[h0] = xo;
            #pragma unroll
            for (int j = 0; j < 4; ++j) {
                const f32x4* w = (const f32x4*)(Wr + (size_t)(h0 + j) * NE);
                f32x4 w0 = w[0], w1 = w[1];
                float xs = xv[j];
                acc[0] += xs * w0[0]; acc[1] += xs * w0[1];
                acc[2] += xs * w0[2]; acc[3] += xs * w0[3];
                acc[4] += xs * w1[0]; acc[5] += xs * w1[1];
                acc[6] += xs * w1[2]; acc[7] += xs * w1[3];
            }
        }
        #pragma unroll
        for (int e = 0; e < NE; ++e) {
            float v = acc[e];
            #pragma unroll
            for (int off = 32; off > 0; off >>= 1) v += __shfl_down(v, off);
            acc[e] = v;
        }
        if (lane == 0) {
            float lg[NE];
            #pragma unroll
            for (int e = 0; e < NE; ++e) lg[e] = acc[e] + br[e];
            float m = lg[0];
            #pragma unroll
            for (int e = 1; e < NE; ++e) m = fmaxf(m, lg[e]);
            float s = 0.f, p[NE];
            #pragma unroll
            for (int e = 0; e < NE; ++e) { p[e] = __expf(lg[e] - m); s += p[e]; }
            float inv = 1.f / s;
            f32x4 p0 = {p[0]*inv, p[1]*inv, p[2]*inv, p[3]*inv};
            f32x4 p1 = {p[4]*inv, p[5]*inv, p[6]*inv, p[7]*inv};
            *(f32x4*)&probs[(size_t)tok * NE]     = p0;
            *(f32x4*)&probs[(size_t)tok * NE + 4] = p1;
            int e0 = 0;
            #pragma unroll
            for (int e = 1; e < NE; ++e) if (lg[e] > lg[e0]) e0 = e;
            int e1 = (e0 == 0) ? 1 : 0;
            #pragma unroll
            for (int e = 0; e < NE; ++e) if (e != e0 && lg[e] > lg[e1]) e1 = e;
            float t1 = __expf(lg[e1] - lg[e0]);
            float w0 = 1.f / (1.f + t1);
            rw[tok * 2 + 0] = w0;
            rw[tok * 2 + 1] = t1 * w0;
            int p0i = atomicAdd(&cnt[e0], 1);
            lists[e0 * TOK + p0i] = (tok << 1);
            int p1i = atomicAdd(&cnt[e1], 1);
            lists[e1 * TOK + p1i] = (tok << 1) | 1;
        }
    }
}

// ======= GEMM machinery: 192M x 256N block, 4 waves (2Mx2N), wave 96x128, ring-2 =======
// LDS-PIPE MODEL (confirmed r12/r13): FLOP/LDS-byte = Mw*Nw/(Mw+Nw) = 49.2.
// Registers: acc[6][8]=192 AGPR + frags + addr ~252 <= 256 -> 2 waves/SIMD.
// LDS = ring-2 x (A[192x32] 12KB + B[256x32] 16KB) = 56 KB -> 2 blocks/CU.
// Ring-2 schedule (7 loads/thread/stage -> vmcnt(7)):
//   iter kt: B1 -> stage(kt+1) -> vmcnt(7) (drains own stage(kt)) -> B2 -> compute(kt).
//   Tail: vmcnt(0).
// Chunk swizzle c' = c ^ ((row>>1)&3) pre-applied on the global source (G21); 0 conflicts.
// Compact grid: 192-row panels; sum ceil(cnt/192) <= 93 -> grid.y = 94.

#define GEMM_FIND_EXPERT()                                                     \
    int pb = blockIdx.y;                                                       \
    int e = 0, row0 = -1, nc = 0, base = 0;                                    \
    {                                                                          \
        int accb = 0, pref = 0;                                                \
        _Pragma("unroll")                                                      \
        for (int i = 0; i < NE; ++i) {                                         \
            int c = cnt[i];                                                    \
            int nb = (c + 191) / 192;                                          \
            if (row0 < 0 && pb < accb + nb) {                                  \
                e = i; row0 = (pb - accb) * 192; nc = c; base = pref;          \
            }                                                                  \
            accb += nb; pref += c;                                             \
        }                                                                      \
        if (row0 < 0) return;                                                  \
    }

#define GEMM_STAGE(kt3, b3)                                                    \
    {                                                                          \
        gl2lds16(ga[0] + (size_t)(kt3) * BK, &As[b3][(0 * 256 + w * 64) * 8]); \
        gl2lds16(ga[1] + (size_t)(kt3) * BK, &As[b3][(1 * 256 + w * 64) * 8]); \
        gl2lds16(ga[2] + (size_t)(kt3) * BK, &As[b3][(2 * 256 + w * 64) * 8]); \
        gl2lds16(gb[0] + (size_t)(kt3) * BK, &Bs[b3][(0 * 256 + w * 64) * 8]); \
        gl2lds16(gb[1] + (size_t)(kt3) * BK, &Bs[b3][(1 * 256 + w * 64) * 8]); \
        gl2lds16(gb[2] + (size_t)(kt3) * BK, &Bs[b3][(2 * 256 + w * 64) * 8]); \
        gl2lds16(gb[3] + (size_t)(kt3) * BK, &Bs[b3][(3 * 256 + w * 64) * 8]); \
    }

#define GEMM_COMPUTE(b)                                                        \
    {                                                                          \
        s16x8 af[6];                                                           \
        _Pragma("unroll")                                                      \
        for (int a = 0; a < 6; ++a) {                                          \
            int r = wr * 96 + a * 16 + rl;                                     \
            af[a] = *(const s16x8*)&As[b][r * 32 + ((q ^ ((r >> 1) & 3)) << 3)]; \
        }                                                                      \
        _Pragma("unroll")                                                      \
        for (int nh = 0; nh < 2; ++nh) {                                       \
            s16x8 bfr[4];                                                      \
            _Pragma("unroll")                                                  \
            for (int ni = 0; ni < 4; ++ni) {                                   \
                int n = wc * 128 + nh * 64 + ni * 16 + rl;                     \
                bfr[ni] = *(const s16x8*)&Bs[b][n * 32 + ((q ^ ((n >> 1) & 3)) << 3)]; \
            }                                                                  \
            _Pragma("unroll")                                                  \
            for (int a = 0; a < 6; ++a)                                        \
                _Pragma("unroll")                                              \
                for (int ni = 0; ni < 4; ++ni)                                 \
                    acc[a][nh * 4 + ni] = mfma_bf16(af[a], bfr[ni], acc[a][nh * 4 + ni]); \
        }                                                                      \
    }

#define GEMM_MAINLOOP(NT)                                                      \
    GEMM_STAGE(0, 0);                                                          \
    for (int kt = 0; kt < (NT); ++kt) {                                        \
        __builtin_amdgcn_s_barrier();                                          \
        if (kt + 1 < (NT)) {                                                   \
            GEMM_STAGE(kt + 1, (kt + 1) & 1);                                  \
            asm volatile("s_waitcnt vmcnt(7)" ::: "memory");                   \
        } else {                                                               \
            asm volatile("s_waitcnt vmcnt(0)" ::: "memory");                   \
        }                                                                      \
        __builtin_amdgcn_s_barrier();                                          \
        GEMM_COMPUTE(kt & 1);                                                  \
    }

// ---------------- GEMM1: hbuf[base+row] = gelu(xb[tok(row)] @ W1T[e]^T + b1[e]) ----------------
__global__ __launch_bounds__(256, 2) void gemm1_kernel(
    const unsigned short* __restrict__ xb, const unsigned short* __restrict__ w1t,
    const float* __restrict__ b1, const int* __restrict__ cnt,
    const int* __restrict__ lists, unsigned short* __restrict__ hbuf)
{
    GEMM_FIND_EXPERT()
    int cb = blockIdx.x * 256;

    __shared__ unsigned short As[2][192 * BK];   // 2 x 12 KiB
    __shared__ unsigned short Bs[2][256 * BK];   // 2 x 16 KiB

    int tid  = threadIdx.x;
    int lane = tid & 63;
    int w    = tid >> 6;     // 0..3
    int wr   = w >> 1;       // M half (rows wr*96..+96)
    int wc   = w & 1;        // N half (cols wc*128..+128)
    int rl   = lane & 15;
    int q    = lane >> 4;    // k-chunk 0..3

    const unsigned short* ga[3];
    const unsigned short* gb[4];
    #pragma unroll
    for (int i = 0; i < 3; ++i) {
        int ch  = i * 256 + tid;
        int row = ch >> 2;
        int kc  = (ch & 3) ^ ((row >> 1) & 3);
        int lr  = row0 + row;
        int tok = (lr < nc) ? (lists[e * TOK + lr] >> 1) : 0;
        ga[i] = xb + (size_t)tok * HD + kc * 8;
    }
    #pragma unroll
    for (int i = 0; i < 4; ++i) {
        int ch  = i * 256 + tid;
        int row = ch >> 2;
        int kc  = (ch & 3) ^ ((row >> 1) & 3);
        gb[i] = w1t + ((size_t)e * FD + cb + row) * HD + kc * 8;
    }

    f32x4 acc[6][8];
    #pragma unroll
    for (int i = 0; i < 6; ++i)
        #pragma unroll
        for (int j = 0; j < 8; ++j) acc[i][j] = (f32x4){0.f, 0.f, 0.f, 0.f};

    GEMM_MAINLOOP(HD / BK)   // 32 iters

    // epilogue: + b1, gelu_fast, bf16 store, expert-packed rows
    int col0 = cb + wc * 128 + rl;
    float b1v[8];
    #pragma unroll
    for (int k = 0; k < 8; ++k)
        b1v[k] = b1[e * FD + col0 + (k >> 2) * 64 + (k & 3) * 16];
    #pragma unroll
    for (int a = 0; a < 6; ++a) {
        #pragma unroll
        for (int j = 0; j < 4; ++j) {
            int grow = row0 + wr * 96 + a * 16 + q * 4 + j;
            if (grow < nc) {
                unsigned short* dst = hbuf + (size_t)(base + grow) * FD + col0;
                #pragma unroll
                for (int k = 0; k < 8; ++k)
                    dst[(k >> 2) * 64 + (k & 3) * 16] =
                        f2bf(gelu_fast(acc[a][k][j] + b1v[k]));
            }
        }
    }
}

// ---------------- GEMM2: y = hbuf[base+row] @ W2T[e]^T + b2[e], scatter to ybuf ----------------
__global__ __launch_bounds__(256, 2) void gemm2_kernel(
    const unsigned short* __restrict__ hbuf, const unsigned short* __restrict__ w2t,
    const float* __restrict__ b2, const int* __restrict__ cnt,
    const int* __restrict__ lists, unsigned short* __restrict__ ybuf)
{
    GEMM_FIND_EXPERT()
    int cb = blockIdx.x * 256;

    __shared__ unsigned short As[2][192 * BK];
    __shared__ unsigned short Bs[2][256 * BK];

    int tid  = threadIdx.x;
    int lane = tid & 63;
    int w    = tid >> 6;
    int wr   = w >> 1;
    int wc   = w & 1;
    int rl   = lane & 15;
    int q    = lane >> 4;

    const unsigned short* ga[3];
    const unsigned short* gb[4];
    #pragma unroll
    for (int i = 0; i < 3; ++i) {
        int ch  = i * 256 + tid;
        int row = ch >> 2;
        int kc  = (ch & 3) ^ ((row >> 1) & 3);
        int lr  = row0 + row;
        int hrow = base + ((lr < nc) ? lr : (nc - 1));
        ga[i] = hbuf + (size_t)hrow * FD + kc * 8;
    }
    #pragma unroll
    for (int i = 0; i < 4; ++i) {
        int ch  = i * 256 + tid;
        int row = ch >> 2;
        int kc  = (ch & 3) ^ ((row >> 1) & 3);
        gb[i] = w2t + ((size_t)e * HD + cb + row) * FD + kc * 8;
    }

    f32x4 acc[6][8];
    #pragma unroll
    for (int i = 0; i < 6; ++i)
        #pragma unroll
        for (int j = 0; j < 8; ++j) acc[i][j] = (f32x4){0.f, 0.f, 0.f, 0.f};

    GEMM_MAINLOOP(FD / BK)   // 128 iters

    int col0 = cb + wc * 128 + rl;
    float b2v[8];
    #pragma unroll
    for (int k = 0; k < 8; ++k)
        b2v[k] = b2[e * HD + col0 + (k >> 2) * 64 + (k & 3) * 16];
    #pragma unroll
    for (int a = 0; a < 6; ++a) {
        #pragma unroll
        for (int j = 0; j < 4; ++j) {
            int grow = row0 + wr * 96 + a * 16 + q * 4 + j;
            if (grow < nc) {
                int entry = lists[e * TOK + grow];
                unsigned short* dst = ybuf + ((size_t)((entry & 1) * TOK + (entry >> 1))) * HD + col0;
                #pragma unroll
                for (int k = 0; k < 8; ++k)
                    dst[(k >> 2) * 64 + (k & 3) * 16] = f2bf(acc[a][k][j] + b2v[k]);
            }
        }
    }
}

// -------- Fused epilogue: gather (out = w0*y0 + w1*y1) + aux1 partial sums --------
__global__ __launch_bounds__(256) void gather_aux_kernel(
    const unsigned short* __restrict__ ybuf, const float* __restrict__ rw,
    float* __restrict__ out, const float* __restrict__ probs,
    float* __restrict__ partial)
{
    if (blockIdx.x < 4096) {
        int g = blockIdx.x * 256 + threadIdx.x;
        int t = g >> 7;
        int h0 = (g & 127) * 8;
        float w0 = rw[t * 2 + 0];
        float w1 = rw[t * 2 + 1];
        s16x8 y0 = *(const s16x8*)&ybuf[(size_t)t * HD + h0];
        s16x8 y1 = *(const s16x8*)&ybuf[((size_t)TOK + t) * HD + h0];
        f32x4 o0, o1;
        #pragma unroll
        for (int j = 0; j < 4; ++j) {
            o0[j] = w0 * bf2f((unsigned short)y0[j])   + w1 * bf2f((unsigned short)y1[j]);
            o1[j] = w0 * bf2f((unsigned short)y0[j+4]) + w1 * bf2f((unsigned short)y1[j+4]);
        }
        *(f32x4*)&out[(size_t)t * HD + h0]     = o0;
        *(f32x4*)&out[(size_t)t * HD + h0 + 4] = o1;
    } else {
        __shared__ float sm[256 * NE];
        int bb  = blockIdx.x - 4096;
        int tid = threadIdx.x;
        int t = bb * 256 + tid;
        const f32x4* p = (const f32x4*)&probs[(size_t)t * NE];
        f32x4 a = p[0], b = p[1];
        sm[tid*NE+0]=a[0]; sm[tid*NE+1]=a[1]; sm[tid*NE+2]=a[2]; sm[tid*NE+3]=a[3];
        sm[tid*NE+4]=b[0]; sm[tid*NE+5]=b[1]; sm[tid*NE+6]=b[2]; sm[tid*NE+7]=b[3];
        __syncthreads();
        for (int s = 128; s > 0; s >>= 1) {
            if (tid < s) {
                #pragma unroll
                for (int e2 = 0; e2 < NE; ++e2)
                    sm[tid * NE + e2] += sm[(tid + s) * NE + e2];
            }
            __syncthreads();
        }
        if (tid < NE) partial[bb * NE + tid] = sm[tid];
    }
}

__global__ __launch_bounds__(64) void aux2_kernel(
    const float* __restrict__ partial, float* __restrict__ outAux)
{
    __shared__ float sm[NE];
    int tid = threadIdx.x;
    if (tid < NE) {
        float s = 0.f;
        for (int b = 0; b < 32; ++b) s += partial[b * NE + tid];
        sm[tid] = s;
    }
    __syncthreads();
    if (tid == 0) {
        float ssum = 0.f;
        #pragma unroll
        for (int e2 = 0; e2 < NE; ++e2) {
            float v = sm[e2] * (1.f / (float)TOK);
            ssum += v * v;
        }
        outAux[0] = (float)NE * ssum;
    }
}

extern "C" void kernel_launch(void* const* d_in, const int* in_sizes, int n_in,
                              void* d_out, int out_size, void* d_ws, size_t ws_size,
                              hipStream_t stream) {
    const float* x  = (const float*)d_in[0];
    const float* W1 = (const float*)d_in[1];
    const float* b1 = (const float*)d_in[2];
    const float* W2 = (const float*)d_in[3];
    const float* b2 = (const float*)d_in[4];
    const float* Wr = (const float*)d_in[5];
    const float* br = (const float*)d_in[6];
    float* out = (float*)d_out;
    char* ws = (char*)d_ws;

    int*   cnt   = (int*)(ws + WS_CNT);
    float* rw    = (float*)(ws + WS_RW);
    int*   lists = (int*)(ws + WS_LST);
    float* probs = (float*)(ws + WS_PRB);
    float* part  = (float*)(ws + WS_PART);
    unsigned short* xb   = (unsigned short*)(ws + WS_XB);
    unsigned short* w1t  = (unsigned short*)(ws + WS_W1T);
    unsigned short* w2t  = (unsigned short*)(ws + WS_W2T);
    unsigned short* hbuf = (unsigned short*)(ws + WS_H);
    unsigned short* ybuf = (unsigned short*)(ws + WS_Y);

    hipMemsetAsync(ws, 0, 64, stream);  // zero cnt
    // Fused prep: 64x64 transposes (x<2048) + router (x>=2048)
    prep_kernel<<<dim3(2304, NE), 256, 0, stream>>>(W1, w1t, W2, w2t,
                                                    x, Wr, br, cnt, lists, rw, probs, xb);
    // Compact grids: y = padded global 192-row panel (sum ceil(cnt/192) <= 93)
    gemm1_kernel<<<dim3(FD / 256, 94), 256, 0, stream>>>(xb, w1t, b1, cnt, lists, hbuf);
    gemm2_kernel<<<dim3(HD / 256, 94), 256, 0, stream>>>(hbuf, w2t, b2, cnt, lists, ybuf);
    gather_aux_kernel<<<4096 + 32, 256, 0, stream>>>(ybuf, rw, out, probs, part);
    aux2_kernel<<<1, 64, 0, stream>>>(part, out + (size_t)TOK * HD);
}

// Round 21
// 588.817 us; speedup vs baseline: 1.0257x; 1.0012x over previous
//
#include <hip/hip_runtime.h>
#include <hip/hip_bf16.h>
#include <stdint.h>

// Problem constants
#define TOK 8192   // B*S
#define HD  1024   // H
#define FD  4096   // F
#define NE  8      // experts
#define BK  32     // K-step

// Workspace layout (bytes). Total ~278 MB.
#define WS_CNT 0
#define WS_RW  1024
#define WS_LST 131072
#define WS_PRB 524288
#define WS_PART 786432
#define WS_XB  ((size_t)1  << 20)   // xb: 8192*1024*2   = 16 MiB
#define WS_W1T ((size_t)18 << 20)   // W1T: 8*4096*1024*2 = 64 MiB
#define WS_W2T ((size_t)84 << 20)   // W2T: 8*1024*4096*2 = 64 MiB
#define WS_H   ((size_t)150 << 20)  // hbuf: 16384*4096*2 = 128 MiB
#define WS_Y   WS_W1T               // ybuf overlays W1T (dead after gemm1)

typedef __attribute__((ext_vector_type(4))) float  f32x4;
typedef __attribute__((ext_vector_type(8))) short  s16x8;
typedef __attribute__((ext_vector_type(4))) short  s16x4;
typedef __attribute__((ext_vector_type(8))) __bf16 bf16x8;

__device__ inline unsigned short f2bf(float f) {
    __hip_bfloat16 h = __float2bfloat16(f);   // RNE
    return __builtin_bit_cast(unsigned short, h);
}
__device__ inline float bf2f(unsigned short s) {
    unsigned u = ((unsigned)s) << 16;
    return __builtin_bit_cast(float, u);
}
__device__ inline f32x4 mfma_bf16(s16x8 a, s16x8 b, f32x4 c) {
    return __builtin_amdgcn_mfma_f32_16x16x32_bf16(
        __builtin_bit_cast(bf16x8, a), __builtin_bit_cast(bf16x8, b), c, 0, 0, 0);
}
// async global->LDS, 16B per lane. LDS dest wave-uniform base (+lane*16 implicit).
__device__ inline void gl2lds16(const void* g, void* l) {
    __builtin_amdgcn_global_load_lds(
        (const __attribute__((address_space(1))) unsigned int*)g,
        (__attribute__((address_space(3))) unsigned int*)l, 16, 0, 0);
}

// Cheap exact-identity tanh-GELU: 0.5u(1+tanh z) == u*p/(1+t), t=e^{-2|z|}, p=(z>=0?1:t).
__device__ inline float gelu_fast(float u) {
    float u2 = u * u;
    float z  = u * fmaf(u2, 0.0356774081f, 0.7978845608f);
    float t  = exp2f(fabsf(z) * -2.885390082f);   // e^{-2|z|}
    float p  = (z >= 0.f) ? 1.f : t;
    return __fdividef(u * p, 1.f + t);
}

// ======== Fused prep (r21): transposes + router, router Wr-access fixed ========
// r19 evidence: halving transpose volume moved prep only 225->214us -> ROUTER is the
// ~210us floor. Old router: lane h0 = i*256+lane*4 -> per Wr-load instruction the wave
// spans 64 lanes at 128-B stride (16B used per line) = 64 cache lines/instr, 32 instr/wave,
// 8192 waves = ~17M line transactions (latency-bound; 5% VALU, 17% HBM).
// FIX: consecutive-h per lane (h = i*64+lane, 16 iters): Wr = 32B/lane CONTIGUOUS
// (wave = dense 2KB span), x scalar 4B (256B/wave), xb scalar 2B (128B/wave).
// Reduce/softmax/top2/atomics tail byte-identical.
// grid = (2304, NE): x<2048 -> transpose tile (x<1024: W1, else W2; y=expert);
// x>=2048 -> router block rb=(x-2048)*NE + y.
__global__ __launch_bounds__(256) void prep_kernel(
    const float* __restrict__ W1, unsigned short* __restrict__ w1t,
    const float* __restrict__ W2, unsigned short* __restrict__ w2t,
    const float* __restrict__ x, const float* __restrict__ Wr,
    const float* __restrict__ br, int* __restrict__ cnt,
    int* __restrict__ lists, float* __restrict__ rw,
    float* __restrict__ probs, unsigned short* __restrict__ xb)
{
    __shared__ unsigned short tile[64][65];
    if (blockIdx.x < 2048) {
        // ---------------- transpose path (r20-identical) ----------------
        int id = blockIdx.x;
        int p  = blockIdx.y;
        const float* src; unsigned short* dst; int R, C, r0, c0;
        if (id < 1024) {                       // W1: C/64 = 64 tiles, R/64 = 16
            src = W1; dst = w1t; R = HD; C = FD;
            c0 = (id & 63) * 64; r0 = (id >> 6) * 64;
        } else {                               // W2: C/64 = 16 tiles, R/64 = 64
            int j = id - 1024;
            src = W2; dst = w2t; R = FD; C = HD;
            c0 = (j & 15) * 64; r0 = (j >> 4) * 64;
        }
        const float* s = src + ((size_t)p * R + r0) * C + c0;
        int cg = threadIdx.x & 15;             // col group of 4
        int rg = threadIdx.x >> 4;             // 0..15
        #pragma unroll
        for (int i = 0; i < 4; ++i) {
            int r = i * 16 + rg;
            f32x4 v = *(const f32x4*)&s[(size_t)r * C + cg * 4];
            tile[r][cg * 4 + 0] = f2bf(v[0]); tile[r][cg * 4 + 1] = f2bf(v[1]);
            tile[r][cg * 4 + 2] = f2bf(v[2]); tile[r][cg * 4 + 3] = f2bf(v[3]);
        }
        __syncthreads();
        unsigned short* d = dst + ((size_t)p * C + c0) * R + r0;
        int hq = (threadIdx.x & 15) * 4;
        int fb = threadIdx.x >> 4;
        #pragma unroll
        for (int i = 0; i < 4; ++i) {
            int c = i * 16 + fb;
            s16x4 v;
            v[0] = (short)tile[hq + 0][c]; v[1] = (short)tile[hq + 1][c];
            v[2] = (short)tile[hq + 2][c]; v[3] = (short)tile[hq + 3][c];
            *(s16x4*)&d[(size_t)c * R + hq] = v;
        }
    } else {
        // ---------------- router path (consecutive-h per lane) ----------------
        int rb   = (blockIdx.x - 2048) * NE + blockIdx.y;   // 0..2047
        int gid  = rb * 256 + threadIdx.x;
        int tok  = gid >> 6;
        int lane = threadIdx.x & 63;
        const float* xr = x + (size_t)tok * HD;
        unsigned short* xbr = xb + (size_t)tok * HD;
        float acc[NE] = {0.f,0.f,0.f,0.f,0.f,0.f,0.f,0.f};
        #pragma unroll
        for (int i = 0; i < 16; ++i) {
            int h = i * 64 + lane;
            float xv = xr[h];
            xbr[h] = f2bf(xv);
            const f32x4* w = (const f32x4*)(Wr + (size_t)h * NE);
            f32x4 w0 = w[0], w1 = w[1];
            acc[0] += xv * w0[0]; acc[1] += xv * w0[1];
            acc[2] += xv * w0[2]; acc[3] += xv * w0[3];
            acc[4] += xv * w1[0]; acc[5] += xv * w1[1];
            acc[6] += xv * w1[2]; acc[7] += xv * w1[3];
        }
        #pragma unroll
        for (int e = 0; e < NE; ++e) {
            float v = acc[e];
            #pragma unroll
            for (int off = 32; off > 0; off >>= 1) v += __shfl_down(v, off);
            acc[e] = v;
        }
        if (lane == 0) {
            float lg[NE];
            #pragma unroll
            for (int e = 0; e < NE; ++e) lg[e] = acc[e] + br[e];
            float m = lg[0];
            #pragma unroll
            for (int e = 1; e < NE; ++e) m = fmaxf(m, lg[e]);
            float s = 0.f, p[NE];
            #pragma unroll
            for (int e = 0; e < NE; ++e) { p[e] = __expf(lg[e] - m); s += p[e]; }
            float inv = 1.f / s;
            f32x4 p0 = {p[0]*inv, p[1]*inv, p[2]*inv, p[3]*inv};
            f32x4 p1 = {p[4]*inv, p[5]*inv, p[6]*inv, p[7]*inv};
            *(f32x4*)&probs[(size_t)tok * NE]     = p0;
            *(f32x4*)&probs[(size_t)tok * NE + 4] = p1;
            int e0 = 0;
            #pragma unroll
            for (int e = 1; e < NE; ++e) if (lg[e] > lg[e0]) e0 = e;
            int e1 = (e0 == 0) ? 1 : 0;
            #pragma unroll
            for (int e = 0; e < NE; ++e) if (e != e0 && lg[e] > lg[e1]) e1 = e;
            float t1 = __expf(lg[e1] - lg[e0]);
            float w0 = 1.f / (1.f + t1);
            rw[tok * 2 + 0] = w0;
            rw[tok * 2 + 1] = t1 * w0;
            int p0i = atomicAdd(&cnt[e0], 1);
            lists[e0 * TOK + p0i] = (tok << 1);
            int p1i = atomicAdd(&cnt[e1], 1);
            lists[e1 * TOK + p1i] = (tok << 1) | 1;
        }
    }
}

// ======= GEMM machinery: 192M x 256N block, 4 waves (2Mx2N), wave 96x128, ring-2 =======
// LDS-PIPE MODEL (confirmed r12/r13): FLOP/LDS-byte = Mw*Nw/(Mw+Nw) = 49.2.
// Registers: acc[6][8]=192 AGPR + frags + addr ~252 <= 256 -> 2 waves/SIMD.
// LDS = ring-2 x (A[192x32] 12KB + B[256x32] 16KB) = 56 KB -> 2 blocks/CU.
// Ring-2 schedule (7 loads/thread/stage -> vmcnt(7)):
//   iter kt: B1 -> stage(kt+1) -> vmcnt(7) (drains own stage(kt)) -> B2 -> compute(kt).
//   Tail: vmcnt(0).
// Chunk swizzle c' = c ^ ((row>>1)&3) pre-applied on the global source (G21); 0 conflicts.
// Compact grid: 192-row panels; sum ceil(cnt/192) <= 93 -> grid.y = 94.

#define GEMM_FIND_EXPERT()                                                     \
    int pb = blockIdx.y;                                                       \
    int e = 0, row0 = -1, nc = 0, base = 0;                                    \
    {                                                                          \
        int accb = 0, pref = 0;                                                \
        _Pragma("unroll")                                                      \
        for (int i = 0; i < NE; ++i) {                                         \
            int c = cnt[i];                                                    \
            int nb = (c + 191) / 192;                                          \
            if (row0 < 0 && pb < accb + nb) {                                  \
                e = i; row0 = (pb - accb) * 192; nc = c; base = pref;          \
            }                                                                  \
            accb += nb; pref += c;                                             \
        }                                                                      \
        if (row0 < 0) return;                                                  \
    }

#define GEMM_STAGE(kt3, b3)                                                    \
    {                                                                          \
        gl2lds16(ga[0] + (size_t)(kt3) * BK, &As[b3][(0 * 256 + w * 64) * 8]); \
        gl2lds16(ga[1] + (size_t)(kt3) * BK, &As[b3][(1 * 256 + w * 64) * 8]); \
        gl2lds16(ga[2] + (size_t)(kt3) * BK, &As[b3][(2 * 256 + w * 64) * 8]); \
        gl2lds16(gb[0] + (size_t)(kt3) * BK, &Bs[b3][(0 * 256 + w * 64) * 8]); \
        gl2lds16(gb[1] + (size_t)(kt3) * BK, &Bs[b3][(1 * 256 + w * 64) * 8]); \
        gl2lds16(gb[2] + (size_t)(kt3) * BK, &Bs[b3][(2 * 256 + w * 64) * 8]); \
        gl2lds16(gb[3] + (size_t)(kt3) * BK, &Bs[b3][(3 * 256 + w * 64) * 8]); \
    }

#define GEMM_COMPUTE(b)                                                        \
    {                                                                          \
        s16x8 af[6];                                                           \
        _Pragma("unroll")                                                      \
        for (int a = 0; a < 6; ++a) {                                          \
            int r = wr * 96 + a * 16 + rl;                                     \
            af[a] = *(const s16x8*)&As[b][r * 32 + ((q ^ ((r >> 1) & 3)) << 3)]; \
        }                                                                      \
        _Pragma("unroll")                                                      \
        for (int nh = 0; nh < 2; ++nh) {                                       \
            s16x8 bfr[4];                                                      \
            _Pragma("unroll")                                                  \
            for (int ni = 0; ni < 4; ++ni) {                                   \
                int n = wc * 128 + nh * 64 + ni * 16 + rl;                     \
                bfr[ni] = *(const s16x8*)&Bs[b][n * 32 + ((q ^ ((n >> 1) & 3)) << 3)]; \
            }                                                                  \
            _Pragma("unroll")                                                  \
            for (int a = 0; a < 6; ++a)                                        \
                _Pragma("unroll")                                              \
                for (int ni = 0; ni < 4; ++ni)                                 \
                    acc[a][nh * 4 + ni] = mfma_bf16(af[a], bfr[ni], acc[a][nh * 4 + ni]); \
        }                                                                      \
    }

#define GEMM_MAINLOOP(NT)                                                      \
    GEMM_STAGE(0, 0);                                                          \
    for (int kt = 0; kt < (NT); ++kt) {                                        \
        __builtin_amdgcn_s_barrier();                                          \
        if (kt + 1 < (NT)) {                                                   \
            GEMM_STAGE(kt + 1, (kt + 1) & 1);                                  \
            asm volatile("s_waitcnt vmcnt(7)" ::: "memory");                   \
        } else {                                                               \
            asm volatile("s_waitcnt vmcnt(0)" ::: "memory");                   \
        }                                                                      \
        __builtin_amdgcn_s_barrier();                                          \
        GEMM_COMPUTE(kt & 1);                                                  \
    }

// ---------------- GEMM1: hbuf[base+row] = gelu(xb[tok(row)] @ W1T[e]^T + b1[e]) ----------------
__global__ __launch_bounds__(256, 2) void gemm1_kernel(
    const unsigned short* __restrict__ xb, const unsigned short* __restrict__ w1t,
    const float* __restrict__ b1, const int* __restrict__ cnt,
    const int* __restrict__ lists, unsigned short* __restrict__ hbuf)
{
    GEMM_FIND_EXPERT()
    int cb = blockIdx.x * 256;

    __shared__ unsigned short As[2][192 * BK];   // 2 x 12 KiB
    __shared__ unsigned short Bs[2][256 * BK];   // 2 x 16 KiB

    int tid  = threadIdx.x;
    int lane = tid & 63;
    int w    = tid >> 6;     // 0..3
    int wr   = w >> 1;       // M half (rows wr*96..+96)
    int wc   = w & 1;        // N half (cols wc*128..+128)
    int rl   = lane & 15;
    int q    = lane >> 4;    // k-chunk 0..3

    const unsigned short* ga[3];
    const unsigned short* gb[4];
    #pragma unroll
    for (int i = 0; i < 3; ++i) {
        int ch  = i * 256 + tid;
        int row = ch >> 2;
        int kc  = (ch & 3) ^ ((row >> 1) & 3);
        int lr  = row0 + row;
        int tok = (lr < nc) ? (lists[e * TOK + lr] >> 1) : 0;
        ga[i] = xb + (size_t)tok * HD + kc * 8;
    }
    #pragma unroll
    for (int i = 0; i < 4; ++i) {
        int ch  = i * 256 + tid;
        int row = ch >> 2;
        int kc  = (ch & 3) ^ ((row >> 1) & 3);
        gb[i] = w1t + ((size_t)e * FD + cb + row) * HD + kc * 8;
    }

    f32x4 acc[6][8];
    #pragma unroll
    for (int i = 0; i < 6; ++i)
        #pragma unroll
        for (int j = 0; j < 8; ++j) acc[i][j] = (f32x4){0.f, 0.f, 0.f, 0.f};

    GEMM_MAINLOOP(HD / BK)   // 32 iters

    // epilogue: + b1, gelu_fast, bf16 store, expert-packed rows
    int col0 = cb + wc * 128 + rl;
    float b1v[8];
    #pragma unroll
    for (int k = 0; k < 8; ++k)
        b1v[k] = b1[e * FD + col0 + (k >> 2) * 64 + (k & 3) * 16];
    #pragma unroll
    for (int a = 0; a < 6; ++a) {
        #pragma unroll
        for (int j = 0; j < 4; ++j) {
            int grow = row0 + wr * 96 + a * 16 + q * 4 + j;
            if (grow < nc) {
                unsigned short* dst = hbuf + (size_t)(base + grow) * FD + col0;
                #pragma unroll
                for (int k = 0; k < 8; ++k)
                    dst[(k >> 2) * 64 + (k & 3) * 16] =
                        f2bf(gelu_fast(acc[a][k][j] + b1v[k]));
            }
        }
    }
}

// ---------------- GEMM2: y = hbuf[base+row] @ W2T[e]^T + b2[e], scatter to ybuf ----------------
__global__ __launch_bounds__(256, 2) void gemm2_kernel(
    const unsigned short* __restrict__ hbuf, const unsigned short* __restrict__ w2t,
    const float* __restrict__ b2, const int* __restrict__ cnt,
    const int* __restrict__ lists, unsigned short* __restrict__ ybuf)
{
    GEMM_FIND_EXPERT()
    int cb = blockIdx.x * 256;

    __shared__ unsigned short As[2][192 * BK];
    __shared__ unsigned short Bs[2][256 * BK];

    int tid  = threadIdx.x;
    int lane = tid & 63;
    int w    = tid >> 6;
    int wr   = w >> 1;
    int wc   = w & 1;
    int rl   = lane & 15;
    int q    = lane >> 4;

    const unsigned short* ga[3];
    const unsigned short* gb[4];
    #pragma unroll
    for (int i = 0; i < 3; ++i) {
        int ch  = i * 256 + tid;
        int row = ch >> 2;
        int kc  = (ch & 3) ^ ((row >> 1) & 3);
        int lr  = row0 + row;
        int hrow = base + ((lr < nc) ? lr : (nc - 1));
        ga[i] = hbuf + (size_t)hrow * FD + kc * 8;
    }
    #pragma unroll
    for (int i = 0; i < 4; ++i) {
        int ch  = i * 256 + tid;
        int row = ch >> 2;
        int kc  = (ch & 3) ^ ((row >> 1) & 3);
        gb[i] = w2t + ((size_t)e * HD + cb + row) * FD + kc * 8;
    }

    f32x4 acc[6][8];
    #pragma unroll
    for (int i = 0; i < 6; ++i)
        #pragma unroll
        for (int j = 0; j < 8; ++j) acc[i][j] = (f32x4){0.f, 0.f, 0.f, 0.f};

    GEMM_MAINLOOP(FD / BK)   // 128 iters

    int col0 = cb + wc * 128 + rl;
    float b2v[8];
    #pragma unroll
    for (int k = 0; k < 8; ++k)
        b2v[k] = b2[e * HD + col0 + (k >> 2) * 64 + (k & 3) * 16];
    #pragma unroll
    for (int a = 0; a < 6; ++a) {
        #pragma unroll
        for (int j = 0; j < 4; ++j) {
            int grow = row0 + wr * 96 + a * 16 + q * 4 + j;
            if (grow < nc) {
                int entry = lists[e * TOK + grow];
                unsigned short* dst = ybuf + ((size_t)((entry & 1) * TOK + (entry >> 1))) * HD + col0;
                #pragma unroll
                for (int k = 0; k < 8; ++k)
                    dst[(k >> 2) * 64 + (k & 3) * 16] = f2bf(acc[a][k][j] + b2v[k]);
            }
        }
    }
}

// -------- Fused epilogue: gather (out = w0*y0 + w1*y1) + aux1 partial sums --------
__global__ __launch_bounds__(256) void gather_aux_kernel(
    const unsigned short* __restrict__ ybuf, const float* __restrict__ rw,
    float* __restrict__ out, const float* __restrict__ probs,
    float* __restrict__ partial)
{
    if (blockIdx.x < 4096) {
        int g = blockIdx.x * 256 + threadIdx.x;
        int t = g >> 7;
        int h0 = (g & 127) * 8;
        float w0 = rw[t * 2 + 0];
        float w1 = rw[t * 2 + 1];
        s16x8 y0 = *(const s16x8*)&ybuf[(size_t)t * HD + h0];
        s16x8 y1 = *(const s16x8*)&ybuf[((size_t)TOK + t) * HD + h0];
        f32x4 o0, o1;
        #pragma unroll
        for (int j = 0; j < 4; ++j) {
            o0[j] = w0 * bf2f((unsigned short)y0[j])   + w1 * bf2f((unsigned short)y1[j]);
            o1[j] = w0 * bf2f((unsigned short)y0[j+4]) + w1 * bf2f((unsigned short)y1[j+4]);
        }
        *(f32x4*)&out[(size_t)t * HD + h0]     = o0;
        *(f32x4*)&out[(size_t)t * HD + h0 + 4] = o1;
    } else {
        __shared__ float sm[256 * NE];
        int bb  = blockIdx.x - 4096;
        int tid = threadIdx.x;
        int t = bb * 256 + tid;
        const f32x4* p = (const f32x4*)&probs[(size_t)t * NE];
        f32x4 a = p[0], b = p[1];
        sm[tid*NE+0]=a[0]; sm[tid*NE+1]=a[1]; sm[tid*NE+2]=a[2]; sm[tid*NE+3]=a[3];
        sm[tid*NE+4]=b[0]; sm[tid*NE+5]=b[1]; sm[tid*NE+6]=b[2]; sm[tid*NE+7]=b[3];
        __syncthreads();
        for (int s = 128; s > 0; s >>= 1) {
            if (tid < s) {
                #pragma unroll
                for (int e2 = 0; e2 < NE; ++e2)
                    sm[tid * NE + e2] += sm[(tid + s) * NE + e2];
            }
            __syncthreads();
        }
        if (tid < NE) partial[bb * NE + tid] = sm[tid];
    }
}

__global__ __launch_bounds__(64) void aux2_kernel(
    const float* __restrict__ partial, float* __restrict__ outAux)
{
    __shared__ float sm[NE];
    int tid = threadIdx.x;
    if (tid < NE) {
        float s = 0.f;
        for (int b = 0; b < 32; ++b) s += partial[b * NE + tid];
        sm[tid] = s;
    }
    __syncthreads();
    if (tid == 0) {
        float ssum = 0.f;
        #pragma unroll
        for (int e2 = 0; e2 < NE; ++e2) {
            float v = sm[e2] * (1.f / (float)TOK);
            ssum += v * v;
        }
        outAux[0] = (float)NE * ssum;
    }
}

extern "C" void kernel_launch(void* const* d_in, const int* in_sizes, int n_in,
                              void* d_out, int out_size, void* d_ws, size_t ws_size,
                              hipStream_t stream) {
    const float* x  = (const float*)d_in[0];
    const float* W1 = (const float*)d_in[1];
    const float* b1 = (const float*)d_in[2];
    const float* W2 = (const float*)d_in[3];
    const float* b2 = (const float*)d_in[4];
    const float* Wr = (const float*)d_in[5];
    const float* br = (const float*)d_in[6];
    float* out = (float*)d_out;
    char* ws = (char*)d_ws;

    int*   cnt   = (int*)(ws + WS_CNT);
    float* rw    = (float*)(ws + WS_RW);
    int*   lists = (int*)(ws + WS_LST);
    float* probs = (float*)(ws + WS_PRB);
    float* part  = (float*)(ws + WS_PART);
    unsigned short* xb   = (unsigned short*)(ws + WS_XB);
    unsigned short* w1t  = (unsigned short*)(ws + WS_W1T);
    unsigned short* w2t  = (unsigned short*)(ws + WS_W2T);
    unsigned short* hbuf = (unsigned short*)(ws + WS_H);
    unsigned short* ybuf = (unsigned short*)(ws + WS_Y);

    hipMemsetAsync(ws, 0, 64, stream);  // zero cnt
    // Fused prep: 64x64 transposes (x<2048) + router (x>=2048, contiguous-Wr access)
    prep_kernel<<<dim3(2304, NE), 256, 0, stream>>>(W1, w1t, W2, w2t,
                                                    x, Wr, br, cnt, lists, rw, probs, xb);
    // Compact grids: y = padded global 192-row panel (sum ceil(cnt/192) <= 93)
    gemm1_kernel<<<dim3(FD / 256, 94), 256, 0, stream>>>(xb, w1t, b1, cnt, lists, hbuf);
    gemm2_kernel<<<dim3(HD / 256, 94), 256, 0, stream>>>(hbuf, w2t, b2, cnt, lists, ybuf);
    gather_aux_kernel<<<4096 + 32, 256, 0, stream>>>(ybuf, rw, out, probs, part);
    aux2_kernel<<<1, 64, 0, stream>>>(part, out + (size_t)TOK * HD);
}